// Round 12
// baseline (7388.142 us; speedup 1.0000x reference)
//
#include <hip/hip_runtime.h>
#include <hip/hip_bf16.h>
#include <stdint.h>

#define B_SZ 2048
#define H_SZ 1024
#define S_SZ 128
#define G4   4096
#define BK   64
#define NKK  16            // K phases per step
#define BM   64            // batch rows per block
#define NXP  8             // pred partials per row (one per col-group)
#define NBLK 256

typedef short short8 __attribute__((ext_vector_type(8)));
typedef int   intx4  __attribute__((ext_vector_type(4)));
typedef float floatx4 __attribute__((ext_vector_type(4)));

#define AS1 __attribute__((address_space(1)))
#define AS3 __attribute__((address_space(3)))

// Persistent device buffers (fully rewritten/reset on every kernel_launch).
// g_Wp LINEAR (B fragments are read directly global->VGPR; cached+immutable
// -> L2-resident per col-group, safe under the release-only barrier).
// g_h LINEAR; crosses blocks -> read ONLY via sc0/sc1 bypass (r8-proven).
// g_pp crosses blocks -> agent-scope atomic loads (r8-proven).
__device__ ushort g_Wp[G4 * H_SZ];       // packed W_hh bf16: row j=(h/16)*64+gate*16+(h%16)
__device__ ushort g_h[2][B_SZ * H_SZ];   // hidden bf16 ping-pong
__device__ float  g_wih[G4];             // packed W_ih
__device__ float  g_bias[G4];            // packed b_ih + b_hh
__device__ float  g_pp[2][B_SZ][NXP];    // pred partials [t&1][row][grp]
__device__ unsigned g_leaf[8 * 32];      // barrier leaves (128B apart)
__device__ unsigned g_root;
__device__ unsigned g_gen;

__device__ __forceinline__ ushort f2bf(float f) {
  unsigned u = __float_as_uint(f);
  return (ushort)((u + 0x7FFFu + ((u >> 16) & 1u)) >> 16);
}
__device__ __forceinline__ float fsig(float x) { return 1.f / (1.f + __expf(-x)); }
__device__ __forceinline__ float ftanh(float x) { return 1.f - 2.f / (__expf(2.f * x) + 1.f); }
__device__ __forceinline__ short8 as_s8(intx4 v) { return __builtin_bit_cast(short8, v); }

// RELEASE-ONLY two-level grid barrier (r8-proven replay-stable). Entry
// __syncthreads drains each wave's stores into L2; tid0's release fence
// writes dirty L2 back to LLC. No invalidate: every cross-block read path
// bypasses L2 (sc0sc1 / atomics); cached data (W, biases, Wfc) is immutable.
__device__ __forceinline__ void grid_barrier(int grp) {
  __syncthreads();
  if (threadIdx.x == 0) {
    __builtin_amdgcn_fence(__ATOMIC_RELEASE, "agent");
    unsigned gen = __hip_atomic_load(&g_gen, __ATOMIC_RELAXED, __HIP_MEMORY_SCOPE_AGENT);
    unsigned a = __hip_atomic_fetch_add(&g_leaf[grp * 32], 1u, __ATOMIC_RELAXED,
                                        __HIP_MEMORY_SCOPE_AGENT);
    if (a == 31u) {
      __hip_atomic_store(&g_leaf[grp * 32], 0u, __ATOMIC_RELAXED, __HIP_MEMORY_SCOPE_AGENT);
      unsigned r = __hip_atomic_fetch_add(&g_root, 1u, __ATOMIC_RELAXED,
                                          __HIP_MEMORY_SCOPE_AGENT);
      if (r == 7u) {
        __hip_atomic_store(&g_root, 0u, __ATOMIC_RELAXED, __HIP_MEMORY_SCOPE_AGENT);
        __hip_atomic_store(&g_gen, gen + 1u, __ATOMIC_RELAXED, __HIP_MEMORY_SCOPE_AGENT);
      } else {
        while (__hip_atomic_load(&g_gen, __ATOMIC_RELAXED, __HIP_MEMORY_SCOPE_AGENT) == gen)
          __builtin_amdgcn_s_sleep(2);
      }
    } else {
      while (__hip_atomic_load(&g_gen, __ATOMIC_RELAXED, __HIP_MEMORY_SCOPE_AGENT) == gen)
        __builtin_amdgcn_s_sleep(2);
    }
    asm volatile("" ::: "memory");
  }
  __syncthreads();
}

// ---------------- prep kernels ----------------

__global__ __launch_bounds__(256) void prep_wpack(const float* __restrict__ Whh) {
  const int gid = blockIdx.x * 256 + threadIdx.x;  // 524288
  const int j   = gid >> 7;                        // packed row 0..4095
  const int k8  = (gid & 127) << 3;                // k offset
  const int gate = (j >> 4) & 3;
  const int h    = ((j >> 6) << 4) | (j & 15);
  const float* src = Whh + (size_t)(gate * H_SZ + h) * H_SZ + k8;
  floatx4 a = *(const floatx4*)src;
  floatx4 b = *(const floatx4*)(src + 4);
  short8 o;
#pragma unroll
  for (int i = 0; i < 4; ++i) o[i] = (short)f2bf(a[i]);
#pragma unroll
  for (int i = 0; i < 4; ++i) o[4 + i] = (short)f2bf(b[i]);
  *(short8*)&g_Wp[(size_t)j * H_SZ + k8] = o;
}

__global__ __launch_bounds__(256) void prep_misc(const float* __restrict__ Wih,
                                                 const float* __restrict__ bih,
                                                 const float* __restrict__ bhh) {
  if (blockIdx.x == 0) {  // reset barrier state every call (determinism)
    if (threadIdx.x == 0) { g_root = 0u; g_gen = 0u; }
    if (threadIdx.x < 8) g_leaf[threadIdx.x * 32] = 0u;
  }
  const int j = blockIdx.x * 256 + threadIdx.x;  // 4096
  const int gate = (j >> 4) & 3;
  const int h    = ((j >> 6) << 4) | (j & 15);
  const int jp   = gate * H_SZ + h;
  g_wih[j]  = Wih[jp];
  g_bias[j] = bih[jp] + bhh[jp];
}

__global__ __launch_bounds__(256) void prep_h(const float* __restrict__ hidden) {
  const int gid = blockIdx.x * 256 + threadIdx.x;  // 262144
  const int o8  = gid << 3;
  short8 o;
#pragma unroll
  for (int i = 0; i < 8; ++i) o[i] = (short)f2bf(hidden[o8 + i]);
  *(short8*)&g_h[0][o8] = o;
}

// ---------------- persistent all-steps kernel ----------------
// 256 blocks x 512 threads (1 block/CU). Col-group grp = bid&7 owns packed
// cols [grp*512, +512) (= h slice [grp*128,+128)); its 32 blocks each own 64
// batch rows (all 2048 covered, h-read duplication d=1). W panel 1 MB/group:
// cached, immutable, L2-resident. B frags load global->VGPR directly (no
// LDS); A (shared by 8 waves) via bypass-reg -> swizzled ds_write.
__global__ __launch_bounds__(512, 1)
void lstm_persistent(const float* __restrict__ cell,
                     const float* __restrict__ Wfc,
                     const float* __restrict__ bfc,
                     float* __restrict__ out) {
  __shared__ ushort Al[2][BM * BK];   // 2 x 8KB
  __shared__ float  xbuf[BM];
  __shared__ float  predp[8 * BM];

  const int tid  = threadIdx.x;
  const int lane = tid & 63;
  const int wid  = tid >> 6;                  // 0..7
  const int bid  = blockIdx.x;
  const int grp  = bid & 7;                   // col-group (and barrier leaf)
  const int brow = (bid >> 3) * BM;           // 64 rows per block
  const int lr = lane & 15, lk = lane >> 4;

  // A staging: thread bypass-loads h[brow+row0][col0*8 .. +8) per phase
  const int row0 = tid >> 3, col0 = tid & 7;
  const size_t abase = (size_t)(brow + row0) * H_SZ + (size_t)col0 * 8;
  const int awoff = row0 * BK + ((col0 ^ (row0 & 7)) << 3);
  ushort* const awA = &Al[0][awoff];
  ushort* const awB = &Al[1][awoff];

  // a-frag ds_read offsets (r2/r11-proven zero-conflict XOR pattern)
  const int ar0 = (0 * 16 + lr) * BK, ar1 = (1 * 16 + lr) * BK;
  const int ar2 = (2 * 16 + lr) * BK, ar3 = (3 * 16 + lr) * BK;
  const int cx0 = (lk * 8) ^ ((lr & 7) << 3);
  const int cx1 = (32 + lk * 8) ^ ((lr & 7) << 3);

  // hoisted epilogue constants
  const int hcol = grp * 128 + wid * 16 + lr;   // global h index
  float wih[4], bb[4];
#pragma unroll
  for (int n = 0; n < 4; ++n) {
    const int col = grp * 512 + wid * 64 + n * 16 + lr;
    wih[n] = g_wih[col];
    bb[n]  = g_bias[col];
  }

  // cell state in registers for the whole sequence
  float creg[4][4];
#pragma unroll
  for (int m = 0; m < 4; ++m)
#pragma unroll
    for (int r = 0; r < 4; ++r) {
      const int row_l = m * 16 + lk * 4 + r;
      creg[m][r] = cell[(size_t)(brow + row_l) * H_SZ + hcol];
    }

#define LB(D, P, O)                                                         \
  asm volatile("global_load_dwordx4 %0, %1, off offset:" #O                 \
               : "=v"(D) : "v"(P));
#define ISSUE_A(R, KK)                                                      \
  { const ushort* ap_ = hin + abase + (KK) * BK;                            \
    asm volatile("global_load_dwordx4 %0, %1, off sc0 sc1"                  \
                 : "=v"(R) : "v"(ap_)); }
#define ISSUE_B_0                                                           \
  { LB(b000, wb0, 0) LB(b001, wb0, 64) LB(b010, wb1, 0) LB(b011, wb1, 64)  \
    LB(b020, wb2, 0) LB(b021, wb2, 64) LB(b030, wb3, 0) LB(b031, wb3, 64)  \
    wb0 += 64; wb1 += 64; wb2 += 64; wb3 += 64; }
#define ISSUE_B_1                                                           \
  { LB(b100, wb0, 0) LB(b101, wb0, 64) LB(b110, wb1, 0) LB(b111, wb1, 64)  \
    LB(b120, wb2, 0) LB(b121, wb2, 64) LB(b130, wb3, 0) LB(b131, wb3, 64)  \
    wb0 += 64; wb1 += 64; wb2 += 64; wb3 += 64; }

#define MF(A, B, M, N) acc[M][N] = __builtin_amdgcn_mfma_f32_16x16x32_bf16( \
    A, as_s8(B), acc[M][N], 0, 0, 0)
#define CHALF(AB, CX, B0, B1, B2, B3)                                       \
  { short8 a0 = *(const short8*)&Al[AB][ar0 + CX];                          \
    short8 a1 = *(const short8*)&Al[AB][ar1 + CX];                          \
    short8 a2 = *(const short8*)&Al[AB][ar2 + CX];                          \
    short8 a3 = *(const short8*)&Al[AB][ar3 + CX];                          \
    __builtin_amdgcn_s_setprio(1);                                          \
    MF(a0, B0, 0, 0); MF(a0, B1, 0, 1); MF(a0, B2, 0, 2); MF(a0, B3, 0, 3); \
    MF(a1, B0, 1, 0); MF(a1, B1, 1, 1); MF(a1, B2, 1, 2); MF(a1, B3, 1, 3); \
    MF(a2, B0, 2, 0); MF(a2, B1, 2, 1); MF(a2, B2, 2, 2); MF(a2, B3, 2, 3); \
    MF(a3, B0, 3, 0); MF(a3, B1, 3, 1); MF(a3, B2, 3, 2); MF(a3, B3, 3, 3); \
    __builtin_amdgcn_s_setprio(0); }
#define COMPUTE_0                                                           \
  { CHALF(0, cx0, b000, b010, b020, b030)                                   \
    CHALF(0, cx1, b001, b011, b021, b031) }
#define COMPUTE_1                                                           \
  { CHALF(1, cx0, b100, b110, b120, b130)                                   \
    CHALF(1, cx1, b101, b111, b121, b131) }

// Phase: [issue next B-frag set (regs)] [issue A 4 ahead (regs)] ->
// counted vmcnt (drains this phase's B set + A reg; keeps newer in flight)
// -> swizzled ds_write A -> lgkm -> barrier -> MFMA. All LDS WAR hazards
// are dbuf-2 + barrier protected; B never touches LDS.
#define PH(VN, BI, AI, AW, RS, CM)                                          \
  { BI AI                                                                   \
    asm volatile("s_waitcnt vmcnt(" #VN ")" ::: "memory");                  \
    __builtin_amdgcn_sched_barrier(0);                                      \
    *(intx4*)(AW) = RS;                                                     \
    asm volatile("s_waitcnt lgkmcnt(0)" ::: "memory");                      \
    __builtin_amdgcn_sched_barrier(0);                                      \
    __builtin_amdgcn_s_barrier();                                           \
    __builtin_amdgcn_sched_barrier(0);                                      \
    CM }
#define NOP_

#pragma unroll 1
  for (int t = 0; t < S_SZ; ++t) {
    const int p = t & 1;
    const ushort* __restrict__ hin = g_h[p];
    ushort* __restrict__ hout      = g_h[p ^ 1];

    floatx4 acc[4][4];
#pragma unroll
    for (int m = 0; m < 4; ++m)
#pragma unroll
      for (int n = 0; n < 4; ++n) acc[m][n] = {0.f, 0.f, 0.f, 0.f};

    intx4 r0, r1, r2, r3, r4;
    intx4 b000, b001, b010, b011, b020, b021, b030, b031;
    intx4 b100, b101, b110, b111, b120, b121, b130, b131;
    const ushort* wb0 = g_Wp + (size_t)(grp * 512 + wid * 64 + 0 * 16 + lr) * H_SZ + lk * 8;
    const ushort* wb1 = g_Wp + (size_t)(grp * 512 + wid * 64 + 1 * 16 + lr) * H_SZ + lk * 8;
    const ushort* wb2 = g_Wp + (size_t)(grp * 512 + wid * 64 + 2 * 16 + lr) * H_SZ + lk * 8;
    const ushort* wb3 = g_Wp + (size_t)(grp * 512 + wid * 64 + 3 * 16 + lr) * H_SZ + lk * 8;

    // prologue: B(0) frags + A(0..3)
    ISSUE_B_0
    ISSUE_A(r0, 0) ISSUE_A(r1, 1) ISSUE_A(r2, 2) ISSUE_A(r3, 3)

    PH(12, ISSUE_B_1, ISSUE_A(r4, 4),  awA, r0, COMPUTE_0)   // ph0
    PH(10, ISSUE_B_0, ISSUE_A(r0, 5),  awB, r1, COMPUTE_1)   // ph1
    PH(10, ISSUE_B_1, ISSUE_A(r1, 6),  awA, r2, COMPUTE_0)   // ph2
    PH(10, ISSUE_B_0, ISSUE_A(r2, 7),  awB, r3, COMPUTE_1)   // ph3
    PH(10, ISSUE_B_1, ISSUE_A(r3, 8),  awA, r4, COMPUTE_0)   // ph4
    PH(10, ISSUE_B_0, ISSUE_A(r4, 9),  awB, r0, COMPUTE_1)   // ph5
    PH(10, ISSUE_B_1, ISSUE_A(r0, 10), awA, r1, COMPUTE_0)   // ph6
    PH(10, ISSUE_B_0, ISSUE_A(r1, 11), awB, r2, COMPUTE_1)   // ph7
    PH(10, ISSUE_B_1, ISSUE_A(r2, 12), awA, r3, COMPUTE_0)   // ph8
    PH(10, ISSUE_B_0, ISSUE_A(r3, 13), awB, r4, COMPUTE_1)   // ph9
    PH(10, ISSUE_B_1, ISSUE_A(r4, 14), awA, r0, COMPUTE_0)   // ph10
    PH(10, ISSUE_B_0, ISSUE_A(r0, 15), awB, r1, COMPUTE_1)   // ph11
    PH(9,  ISSUE_B_1, NOP_,            awA, r2, COMPUTE_0)   // ph12
    PH(8,  ISSUE_B_0, NOP_,            awB, r3, COMPUTE_1)   // ph13
    PH(8,  ISSUE_B_1, NOP_,            awA, r4, COMPUTE_0)   // ph14
    PH(0,  NOP_,      NOP_,            awB, r0, COMPUTE_1)   // ph15

    // ---------------- epilogue ----------------
    if (t > 0 && tid < BM) {
      float s = bfc[t - 1];
      const float* pr = &g_pp[(t - 1) & 1][brow + tid][0];
#pragma unroll
      for (int g = 0; g < NXP; ++g)
        s += __hip_atomic_load(pr + g, __ATOMIC_RELAXED, __HIP_MEMORY_SCOPE_AGENT);
      xbuf[tid] = s;
      if (grp == 0) out[(size_t)(brow + tid) * S_SZ + (t - 1)] = s;
    }
    __syncthreads();

    const float wfc_l = Wfc[(size_t)t * H_SZ + hcol];  // own-step head weight

#pragma unroll
    for (int m = 0; m < 4; ++m) {
#pragma unroll
      for (int r = 0; r < 4; ++r) {
        const int row_l = m * 16 + lk * 4 + r;
        const float xv = (t > 0) ? xbuf[row_l] : 0.f;
        float gi = acc[m][0][r] + xv * wih[0] + bb[0];
        float gf = acc[m][1][r] + xv * wih[1] + bb[1];
        float gg = acc[m][2][r] + xv * wih[2] + bb[2];
        float go = acc[m][3][r] + xv * wih[3] + bb[3];
        float cn = fsig(gf) * creg[m][r] + fsig(gi) * ftanh(gg);
        creg[m][r] = cn;
        float hv = fsig(go) * ftanh(cn);
        hout[(size_t)(brow + row_l) * H_SZ + hcol] = f2bf(hv);
        // own-step head partial over this group's 16-h slice
        float pp = hv * wfc_l;
        pp += __shfl_xor(pp, 1);
        pp += __shfl_xor(pp, 2);
        pp += __shfl_xor(pp, 4);
        pp += __shfl_xor(pp, 8);
        if (lr == 0) predp[wid * BM + row_l] = pp;
      }
    }
    __syncthreads();
    if (tid < BM) {
      float s = 0.f;
#pragma unroll
      for (int w = 0; w < 8; ++w) s += predp[w * BM + tid];
      g_pp[p][brow + tid][grp] = s;
    }

    grid_barrier(grp);
  }

  // final head output for t = S-1 (127 odd -> partials in g_pp[1])
  if (grp == 0 && tid < BM) {
    float s = bfc[S_SZ - 1];
    const float* pr = &g_pp[1][brow + tid][0];
#pragma unroll
    for (int g = 0; g < NXP; ++g)
      s += __hip_atomic_load(pr + g, __ATOMIC_RELAXED, __HIP_MEMORY_SCOPE_AGENT);
    out[(size_t)(brow + tid) * S_SZ + (S_SZ - 1)] = s;
  }
#undef LB
#undef ISSUE_A
#undef ISSUE_B_0
#undef ISSUE_B_1
#undef MF
#undef CHALF
#undef COMPUTE_0
#undef COMPUTE_1
#undef PH
#undef NOP_
}

extern "C" void kernel_launch(void* const* d_in, const int* in_sizes, int n_in,
                              void* d_out, int out_size, void* d_ws, size_t ws_size,
                              hipStream_t stream) {
  const float* hidden = (const float*)d_in[0];
  const float* cell   = (const float*)d_in[1];
  const float* W_ih   = (const float*)d_in[2];
  const float* W_hh   = (const float*)d_in[3];
  const float* b_ih   = (const float*)d_in[4];
  const float* b_hh   = (const float*)d_in[5];
  const float* W_fc   = (const float*)d_in[6];
  const float* b_fc   = (const float*)d_in[7];
  float* out = (float*)d_out;

  prep_wpack<<<2048, 256, 0, stream>>>(W_hh);
  prep_misc<<<16, 256, 0, stream>>>(W_ih, b_ih, b_hh);
  prep_h<<<1024, 256, 0, stream>>>(hidden);

  lstm_persistent<<<NBLK, 512, 0, stream>>>(cell, W_fc, b_fc, out);
}